// Round 1
// baseline (506.930 us; speedup 1.0000x reference)
//
#include <hip/hip_runtime.h>

#define N_NODES 12288
#define N_EDGES 393216
#define DIN 512
#define DH 256
#define DZ 64

typedef __bf16 bf16x8 __attribute__((ext_vector_type(8)));
typedef float f32x4 __attribute__((ext_vector_type(4)));

static __device__ __forceinline__ unsigned short f2bf(float f) {
    unsigned int u = __float_as_uint(f);
    unsigned int r = (u + 0x7fffu + ((u >> 16) & 1u)) >> 16;
    return (unsigned short)r;
}

// ---- CSR build ----
__global__ __launch_bounds__(256) void k_count(const int* __restrict__ dst, int* __restrict__ deg) {
    int e = blockIdx.x * 256 + threadIdx.x;
    if (e < N_EDGES) atomicAdd(&deg[dst[e]], 1);
}

__global__ __launch_bounds__(256) void k_norm(const int* __restrict__ deg, float* __restrict__ norm) {
    int i = blockIdx.x * 256 + threadIdx.x;
    if (i < N_NODES) norm[i] = rsqrtf((float)deg[i] + 1.0f);
}

__global__ __launch_bounds__(1024) void k_scan(const int* __restrict__ cnt, int* __restrict__ rp) {
    __shared__ int sp[1024];
    int t = threadIdx.x;
    int base = t * 12;
    int loc[12];
    int s = 0;
#pragma unroll
    for (int j = 0; j < 12; ++j) { loc[j] = s; s += cnt[base + j]; }
    sp[t] = s;
    __syncthreads();
    for (int off = 1; off < 1024; off <<= 1) {
        int v = (t >= off) ? sp[t - off] : 0;
        __syncthreads();
        sp[t] += v;
        __syncthreads();
    }
    int pre = (t == 0) ? 0 : sp[t - 1];
#pragma unroll
    for (int j = 0; j < 12; ++j) rp[base + j] = pre + loc[j];
    if (t == 1023) rp[N_NODES] = sp[1023];
}

__global__ __launch_bounds__(256) void k_scatter(const int* __restrict__ src, const int* __restrict__ dst,
                                                 const int* __restrict__ rp, int* __restrict__ cursor,
                                                 int* __restrict__ ssrc) {
    int e = blockIdx.x * 256 + threadIdx.x;
    if (e < N_EDGES) {
        int d = dst[e];
        int pos = atomicAdd(&cursor[d], 1);
        ssrc[rp[d] + pos] = src[e];
    }
}

// ---- bf16 conversions ----
__global__ __launch_bounds__(256) void k_cvtX(const float* __restrict__ X, unsigned short* __restrict__ Xb) {
    int i = blockIdx.x * 256 + threadIdx.x;  // over N*DIN/4
    float4 v = ((const float4*)X)[i];
    ushort4 o;
    o.x = f2bf(v.x); o.y = f2bf(v.y); o.z = f2bf(v.z); o.w = f2bf(v.w);
    ((ushort4*)Xb)[i] = o;
}

__global__ __launch_bounds__(256) void k_cvtW1T(const float* __restrict__ W1, unsigned short* __restrict__ W1T) {
    int i = blockIdx.x * 256 + threadIdx.x;  // 512*256 elements, i = c*512 + k
    int c = i >> 9, k = i & 511;
    W1T[i] = f2bf(W1[k * DH + c]);
}

// ---- h1 = X @ W1 + b1  (bf16 MFMA, f32 out) ----
__global__ __launch_bounds__(256) void k_gemm1(const unsigned short* __restrict__ Xb,
                                               const unsigned short* __restrict__ W1T,
                                               const float* __restrict__ b1, float* __restrict__ h1) {
    int wid = threadIdx.x >> 6;
    int lane = threadIdx.x & 63;
    int ln = lane & 15, kg = lane >> 4;
    int rb = blockIdx.x * 256 + wid * 64;
    int cb = blockIdx.y * 64;
    f32x4 acc[4][4] = {};
    const unsigned short* xa = Xb + (size_t)(rb + ln) * DIN + kg * 8;
    const unsigned short* wb = W1T + (size_t)(cb + ln) * DIN + kg * 8;
    for (int ks = 0; ks < 16; ++ks) {
        int k0 = ks * 32;
        bf16x8 a[4], b[4];
#pragma unroll
        for (int m = 0; m < 4; ++m) a[m] = *(const bf16x8*)(xa + (size_t)m * 16 * DIN + k0);
#pragma unroll
        for (int n = 0; n < 4; ++n) b[n] = *(const bf16x8*)(wb + (size_t)n * 16 * DIN + k0);
#pragma unroll
        for (int m = 0; m < 4; ++m)
#pragma unroll
            for (int n = 0; n < 4; ++n)
                acc[m][n] = __builtin_amdgcn_mfma_f32_16x16x32_bf16(a[m], b[n], acc[m][n], 0, 0, 0);
    }
#pragma unroll
    for (int m = 0; m < 4; ++m)
#pragma unroll
        for (int n = 0; n < 4; ++n)
#pragma unroll
            for (int r = 0; r < 4; ++r) {
                int row = rb + m * 16 + kg * 4 + r;
                int col = cb + n * 16 + ln;
                h1[row * DH + col] = acc[m][n][r] + b1[col];
            }
}

// ---- agg1: H = relu(norm*(segsum(h1[src]*norm[src]) + norm*h1)); tvec = S + norm ----
__global__ __launch_bounds__(256) void k_agg1(const float* __restrict__ h1, const int* __restrict__ rp,
                                              const int* __restrict__ ssrc, const float* __restrict__ norm,
                                              float* __restrict__ Hout, float* __restrict__ tvec) {
    int i = blockIdx.x;
    int t = threadIdx.x;
    int beg = rp[i], end = rp[i + 1];
    float acc = 0.f, ssum = 0.f;
    for (int e = beg; e < end; ++e) {
        int s = ssrc[e];
        float ns = norm[s];
        acc = fmaf(h1[(size_t)s * DH + t], ns, acc);
        ssum += ns;
    }
    float ni = norm[i];
    float hv = h1[(size_t)i * DH + t];
    float o = ni * (acc + ni * hv);
    Hout[(size_t)i * DH + t] = fmaxf(o, 0.f);
    if (t == 0) tvec[i] = ssum + ni;
}

// ---- agg2: M = segsum(H[src]*norm[src]) + norm*H; then logsig, mus, Z fused ----
__global__ __launch_bounds__(256) void k_agg2(const float* __restrict__ H, const int* __restrict__ rp,
                                              const int* __restrict__ ssrc, const float* __restrict__ norm,
                                              const float* __restrict__ tvec,
                                              const float* __restrict__ Wmu, const float* __restrict__ bmu,
                                              const float* __restrict__ Wsig, const float* __restrict__ bsig,
                                              const float* __restrict__ eps,
                                              float* __restrict__ mus_out, float* __restrict__ logs_out,
                                              unsigned short* __restrict__ Zb) {
    __shared__ float sM[DH];
    __shared__ float red[DH];
    int i = blockIdx.x;
    int t = threadIdx.x;
    int beg = rp[i], end = rp[i + 1];
    float acc = 0.f;
    for (int e = beg; e < end; ++e) {
        int s = ssrc[e];
        acc = fmaf(H[(size_t)s * DH + t], norm[s], acc);
    }
    float ni = norm[i], tv = tvec[i];
    float m = acc + ni * H[(size_t)i * DH + t];
    sM[t] = m;
    red[t] = m * Wsig[t];
    __syncthreads();
    for (int s2 = 128; s2 > 0; s2 >>= 1) {
        if (t < s2) red[t] += red[t + s2];
        __syncthreads();
    }
    if (t == 0) {
        float ls = ni * (red[0] + bsig[0] * tv);
        logs_out[i] = ls;
        red[0] = ls;
    }
    __syncthreads();
    float logsig = red[0];
    float sig = expf(0.5f * logsig);
    int c = t & 63, p = t >> 6;
    float part = 0.f;
#pragma unroll 8
    for (int j = 0; j < 64; ++j) {
        int k = p * 64 + j;
        part = fmaf(sM[k], Wmu[k * DZ + c], part);
    }
    __syncthreads();   // everyone done reading red[0]
    red[t] = part;
    __syncthreads();
    if (p == 0) {
        float dot = red[c] + red[64 + c] + red[128 + c] + red[192 + c];
        float mu = ni * (dot + bmu[c] * tv);
        mus_out[(size_t)i * DZ + c] = mu;
        float z = mu + sig * eps[(size_t)i * DZ + c];
        Zb[(size_t)i * DZ + c] = f2bf(z);
    }
}

// ---- ZZt = Z @ Z^T (bf16 MFMA, f32 nontemporal stores) ----
__global__ __launch_bounds__(256) void k_zzt(const unsigned short* __restrict__ Zb, float* __restrict__ out) {
    int wid = threadIdx.x >> 6;
    int lane = threadIdx.x & 63;
    int ln = lane & 15, kg = lane >> 4;
    int rb = blockIdx.x * 128 + (wid >> 1) * 64;
    int cb = blockIdx.y * 128 + (wid & 1) * 64;
    bf16x8 a[4][2], b[4][2];
#pragma unroll
    for (int m = 0; m < 4; ++m)
#pragma unroll
        for (int kc = 0; kc < 2; ++kc)
            a[m][kc] = *(const bf16x8*)(Zb + (size_t)(rb + m * 16 + ln) * DZ + kc * 32 + kg * 8);
#pragma unroll
    for (int n = 0; n < 4; ++n)
#pragma unroll
        for (int kc = 0; kc < 2; ++kc)
            b[n][kc] = *(const bf16x8*)(Zb + (size_t)(cb + n * 16 + ln) * DZ + kc * 32 + kg * 8);
    f32x4 acc[4][4] = {};
#pragma unroll
    for (int m = 0; m < 4; ++m)
#pragma unroll
        for (int n = 0; n < 4; ++n) {
            acc[m][n] = __builtin_amdgcn_mfma_f32_16x16x32_bf16(a[m][0], b[n][0], acc[m][n], 0, 0, 0);
            acc[m][n] = __builtin_amdgcn_mfma_f32_16x16x32_bf16(a[m][1], b[n][1], acc[m][n], 0, 0, 0);
        }
#pragma unroll
    for (int m = 0; m < 4; ++m)
#pragma unroll
        for (int n = 0; n < 4; ++n)
#pragma unroll
            for (int r = 0; r < 4; ++r) {
                size_t row = rb + m * 16 + kg * 4 + r;
                size_t col = cb + n * 16 + ln;
                __builtin_nontemporal_store(acc[m][n][r], out + row * (size_t)N_NODES + col);
            }
}

extern "C" void kernel_launch(void* const* d_in, const int* in_sizes, int n_in,
                              void* d_out, int out_size, void* d_ws, size_t ws_size,
                              hipStream_t stream) {
    const float* X = (const float*)d_in[0];
    const int* edge = (const int*)d_in[1];
    const float* W1 = (const float*)d_in[2];
    const float* b1 = (const float*)d_in[3];
    const float* Wmu = (const float*)d_in[4];
    const float* bmu = (const float*)d_in[5];
    const float* Wsig = (const float*)d_in[6];
    const float* bsig = (const float*)d_in[7];
    const float* eps = (const float*)d_in[8];

    const int* esrc = edge;
    const int* edst = edge + N_EDGES;

    char* w = (char*)d_ws;
    int* deg = (int*)w;            w += (size_t)N_NODES * 4;
    int* cursor = (int*)w;         w += (size_t)N_NODES * 4;
    float* norm = (float*)w;       w += (size_t)N_NODES * 4;
    float* tvec = (float*)w;       w += (size_t)N_NODES * 4;
    int* rowptr = (int*)w;         w += (size_t)(N_NODES + 64) * 4;
    int* ssrc = (int*)w;           w += (size_t)N_EDGES * 4;
    unsigned short* Xb = (unsigned short*)w;   w += (size_t)N_NODES * DIN * 2;
    unsigned short* W1T = (unsigned short*)w;  w += (size_t)DIN * DH * 2;
    float* h1 = (float*)w;         w += (size_t)N_NODES * DH * 4;
    float* Hm = (float*)w;         w += (size_t)N_NODES * DH * 4;
    unsigned short* Zb = (unsigned short*)w;   w += (size_t)N_NODES * DZ * 2;

    float* out_zzt = (float*)d_out;
    float* out_mus = out_zzt + (size_t)N_NODES * N_NODES;
    float* out_logs = out_mus + (size_t)N_NODES * DZ;

    hipMemsetAsync(d_ws, 0, (size_t)N_NODES * 8, stream);  // deg + cursor
    k_count<<<N_EDGES / 256, 256, 0, stream>>>(edst, deg);
    k_norm<<<N_NODES / 256, 256, 0, stream>>>(deg, norm);
    k_scan<<<1, 1024, 0, stream>>>(deg, rowptr);
    k_scatter<<<N_EDGES / 256, 256, 0, stream>>>(esrc, edst, rowptr, cursor, ssrc);
    k_cvtX<<<(N_NODES * DIN / 4) / 256, 256, 0, stream>>>(X, Xb);
    k_cvtW1T<<<(DIN * DH) / 256, 256, 0, stream>>>(W1, W1T);
    k_gemm1<<<dim3(N_NODES / 256, DH / 64), 256, 0, stream>>>(Xb, W1T, b1, h1);
    k_agg1<<<N_NODES, 256, 0, stream>>>(h1, rowptr, ssrc, norm, Hm, tvec);
    k_agg2<<<N_NODES, 256, 0, stream>>>(Hm, rowptr, ssrc, norm, tvec, Wmu, bmu, Wsig, bsig, eps,
                                        out_mus, out_logs, Zb);
    k_zzt<<<dim3(N_NODES / 128, N_NODES / 128), 256, 0, stream>>>(Zb, out_zzt);
}

// Round 2
// 404.742 us; speedup vs baseline: 1.2525x; 1.2525x over previous
//
#include <hip/hip_runtime.h>

#define N_NODES 12288
#define N_EDGES 393216
#define DIN 512
#define DH 256
#define DZ 64

typedef __bf16 bf16x8 __attribute__((ext_vector_type(8)));
typedef float f32x4 __attribute__((ext_vector_type(4)));

static __device__ __forceinline__ unsigned short f2bf(float f) {
    unsigned int u = __float_as_uint(f);
    unsigned int r = (u + 0x7fffu + ((u >> 16) & 1u)) >> 16;
    return (unsigned short)r;
}
static __device__ __forceinline__ float bf2f(unsigned short u) {
    return __uint_as_float((unsigned int)u << 16);
}

// ---- prep: cvt X->bf16, cvt W1->W1T bf16, count degrees (fused, independent) ----
__global__ __launch_bounds__(256) void k_prep(const float* __restrict__ X, unsigned short* __restrict__ Xb,
                                              const float* __restrict__ W1, unsigned short* __restrict__ W1T,
                                              const int* __restrict__ dst, int* __restrict__ deg) {
    int b = blockIdx.x;
    if (b < 6144) {                       // X: 12288*512/4 elems of float4
        int i = b * 256 + threadIdx.x;
        float4 v = ((const float4*)X)[i];
        ushort4 o;
        o.x = f2bf(v.x); o.y = f2bf(v.y); o.z = f2bf(v.z); o.w = f2bf(v.w);
        ((ushort4*)Xb)[i] = o;
    } else if (b < 6656) {                // W1T: 512*256 elems, i = c*512+k
        int i = (b - 6144) * 256 + threadIdx.x;
        int c = i >> 9, k = i & 511;
        W1T[i] = f2bf(W1[k * DH + c]);
    } else {                              // degree count: 1536*256 = 393216 edges
        int e = (b - 6656) * 256 + threadIdx.x;
        atomicAdd(&deg[dst[e]], 1);
    }
}

// ---- scan (rowptr) + norm fused ----
__global__ __launch_bounds__(1024) void k_scan(const int* __restrict__ cnt, int* __restrict__ rp,
                                               float* __restrict__ norm) {
    __shared__ int sp[1024];
    int t = threadIdx.x;
    int base = t * 12;
    int loc[12];
    int s = 0;
#pragma unroll
    for (int j = 0; j < 12; ++j) {
        int c = cnt[base + j];
        norm[base + j] = rsqrtf((float)c + 1.0f);
        loc[j] = s; s += c;
    }
    sp[t] = s;
    __syncthreads();
    for (int off = 1; off < 1024; off <<= 1) {
        int v = (t >= off) ? sp[t - off] : 0;
        __syncthreads();
        sp[t] += v;
        __syncthreads();
    }
    int pre = (t == 0) ? 0 : sp[t - 1];
#pragma unroll
    for (int j = 0; j < 12; ++j) rp[base + j] = pre + loc[j];
    if (t == 1023) rp[N_NODES] = sp[1023];
}

__global__ __launch_bounds__(256) void k_scatter(const int* __restrict__ src, const int* __restrict__ dst,
                                                 const int* __restrict__ rp, int* __restrict__ cursor,
                                                 int* __restrict__ ssrc) {
    int e = blockIdx.x * 256 + threadIdx.x;
    int d = dst[e];
    int pos = atomicAdd(&cursor[d], 1);
    ssrc[rp[d] + pos] = src[e];
}

// ---- g1 = norm .* (X @ W1 + b1)  (bf16 MFMA, bf16 out) ----
__global__ __launch_bounds__(256) void k_gemm1(const unsigned short* __restrict__ Xb,
                                               const unsigned short* __restrict__ W1T,
                                               const float* __restrict__ b1, const float* __restrict__ norm,
                                               unsigned short* __restrict__ g1) {
    int wid = threadIdx.x >> 6;
    int lane = threadIdx.x & 63;
    int ln = lane & 15, kg = lane >> 4;
    int rb = blockIdx.x * 256 + wid * 64;
    int cb = blockIdx.y * 64;
    f32x4 acc[4][4] = {};
    const unsigned short* xa = Xb + (size_t)(rb + ln) * DIN + kg * 8;
    const unsigned short* wb = W1T + (size_t)(cb + ln) * DIN + kg * 8;
    for (int ks = 0; ks < 16; ++ks) {
        int k0 = ks * 32;
        bf16x8 a[4], b[4];
#pragma unroll
        for (int m = 0; m < 4; ++m) a[m] = *(const bf16x8*)(xa + (size_t)m * 16 * DIN + k0);
#pragma unroll
        for (int n = 0; n < 4; ++n) b[n] = *(const bf16x8*)(wb + (size_t)n * 16 * DIN + k0);
#pragma unroll
        for (int m = 0; m < 4; ++m)
#pragma unroll
            for (int n = 0; n < 4; ++n)
                acc[m][n] = __builtin_amdgcn_mfma_f32_16x16x32_bf16(a[m], b[n], acc[m][n], 0, 0, 0);
    }
#pragma unroll
    for (int m = 0; m < 4; ++m)
#pragma unroll
        for (int r = 0; r < 4; ++r) {
            int row = rb + m * 16 + kg * 4 + r;
            float ni = norm[row];
#pragma unroll
            for (int n = 0; n < 4; ++n) {
                int col = cb + n * 16 + ln;
                g1[(size_t)row * DH + col] = f2bf(ni * (acc[m][n][r] + b1[col]));
            }
        }
}

// ---- agg1: wave-per-node. G2 = norm .* relu(norm*(sum g1[src] + g1[i])); tvec = sum norm[src]+norm[i] ----
__global__ __launch_bounds__(256) void k_agg1(const unsigned short* __restrict__ g1,
                                              const int* __restrict__ rp, const int* __restrict__ ssrc,
                                              const float* __restrict__ norm,
                                              unsigned short* __restrict__ G2, float* __restrict__ tvec) {
    int w = threadIdx.x >> 6;
    int lane = threadIdx.x & 63;
    int i = blockIdx.x * 4 + w;
    int beg = rp[i], end = rp[i + 1];
    float ax = 0.f, ay = 0.f, az = 0.f, aw = 0.f;
    float ssum = 0.f;
    int co = lane << 2;
#pragma unroll 2
    for (int e = beg; e < end; ++e) {
        int s = ssrc[e];
        ushort4 v = *(const ushort4*)(g1 + ((size_t)s << 8) + co);
        ssum += norm[s];
        ax += bf2f(v.x); ay += bf2f(v.y); az += bf2f(v.z); aw += bf2f(v.w);
    }
    ushort4 sv = *(const ushort4*)(g1 + ((size_t)i << 8) + co);
    ax += bf2f(sv.x); ay += bf2f(sv.y); az += bf2f(sv.z); aw += bf2f(sv.w);
    float ni = norm[i];
    ushort4 o;
    o.x = f2bf(ni * fmaxf(ni * ax, 0.f));
    o.y = f2bf(ni * fmaxf(ni * ay, 0.f));
    o.z = f2bf(ni * fmaxf(ni * az, 0.f));
    o.w = f2bf(ni * fmaxf(ni * aw, 0.f));
    *(ushort4*)(G2 + ((size_t)i << 8) + co) = o;
    if (lane == 0) tvec[i] = ssum + ni;
}

// ---- agg2: wave-per-node. M = sum G2[src] + G2[i]; logsig, mus, Z fused ----
__global__ __launch_bounds__(256) void k_agg2(const unsigned short* __restrict__ G2,
                                              const int* __restrict__ rp, const int* __restrict__ ssrc,
                                              const float* __restrict__ norm, const float* __restrict__ tvec,
                                              const float* __restrict__ Wmu, const float* __restrict__ bmu,
                                              const float* __restrict__ Wsig, const float* __restrict__ bsig,
                                              const float* __restrict__ eps,
                                              float* __restrict__ mus_out, float* __restrict__ logs_out,
                                              unsigned short* __restrict__ Zb) {
    __shared__ float sM[4][DH];
    int w = threadIdx.x >> 6;
    int lane = threadIdx.x & 63;
    int i = blockIdx.x * 4 + w;
    int beg = rp[i], end = rp[i + 1];
    float ax = 0.f, ay = 0.f, az = 0.f, aw = 0.f;
    int co = lane << 2;
#pragma unroll 2
    for (int e = beg; e < end; ++e) {
        int s = ssrc[e];
        ushort4 v = *(const ushort4*)(G2 + ((size_t)s << 8) + co);
        ax += bf2f(v.x); ay += bf2f(v.y); az += bf2f(v.z); aw += bf2f(v.w);
    }
    ushort4 sv = *(const ushort4*)(G2 + ((size_t)i << 8) + co);
    ax += bf2f(sv.x); ay += bf2f(sv.y); az += bf2f(sv.z); aw += bf2f(sv.w);

    // logsigma2: dot(M, Wsig) via lane-local partial + butterfly reduce
    const float4 wsg = *(const float4*)(Wsig + co);
    float part = ax * wsg.x + ay * wsg.y + az * wsg.z + aw * wsg.w;
#pragma unroll
    for (int m = 32; m >= 1; m >>= 1) part += __shfl_xor(part, m);
    float ni = norm[i], tv = tvec[i];
    float ls = ni * (part + bsig[0] * tv);
    if (lane == 0) logs_out[i] = ls;
    float sig = expf(0.5f * ls);

    // stage M to LDS, then lane c computes mu[c]
    float4 mv; mv.x = ax; mv.y = ay; mv.z = az; mv.w = aw;
    *(float4*)&sM[w][co] = mv;
    __syncthreads();
    float dot2 = 0.f;
#pragma unroll 4
    for (int k = 0; k < DH; ++k) dot2 = fmaf(sM[w][k], Wmu[k * DZ + lane], dot2);
    float mu = ni * (dot2 + bmu[lane] * tv);
    size_t oidx = ((size_t)i << 6) + lane;
    mus_out[oidx] = mu;
    Zb[oidx] = f2bf(mu + sig * eps[oidx]);
}

// ---- ZZt = Z @ Z^T (bf16 MFMA, f32 nontemporal stores) ----
__global__ __launch_bounds__(256) void k_zzt(const unsigned short* __restrict__ Zb, float* __restrict__ out) {
    int wid = threadIdx.x >> 6;
    int lane = threadIdx.x & 63;
    int ln = lane & 15, kg = lane >> 4;
    int rb = blockIdx.x * 128 + (wid >> 1) * 64;
    int cb = blockIdx.y * 128 + (wid & 1) * 64;
    bf16x8 a[4][2], b[4][2];
#pragma unroll
    for (int m = 0; m < 4; ++m)
#pragma unroll
        for (int kc = 0; kc < 2; ++kc)
            a[m][kc] = *(const bf16x8*)(Zb + (size_t)(rb + m * 16 + ln) * DZ + kc * 32 + kg * 8);
#pragma unroll
    for (int n = 0; n < 4; ++n)
#pragma unroll
        for (int kc = 0; kc < 2; ++kc)
            b[n][kc] = *(const bf16x8*)(Zb + (size_t)(cb + n * 16 + ln) * DZ + kc * 32 + kg * 8);
    f32x4 acc[4][4] = {};
#pragma unroll
    for (int m = 0; m < 4; ++m)
#pragma unroll
        for (int n = 0; n < 4; ++n) {
            acc[m][n] = __builtin_amdgcn_mfma_f32_16x16x32_bf16(a[m][0], b[n][0], acc[m][n], 0, 0, 0);
            acc[m][n] = __builtin_amdgcn_mfma_f32_16x16x32_bf16(a[m][1], b[n][1], acc[m][n], 0, 0, 0);
        }
#pragma unroll
    for (int m = 0; m < 4; ++m)
#pragma unroll
        for (int n = 0; n < 4; ++n)
#pragma unroll
            for (int r = 0; r < 4; ++r) {
                size_t row = rb + m * 16 + kg * 4 + r;
                size_t col = cb + n * 16 + ln;
                __builtin_nontemporal_store(acc[m][n][r], out + row * (size_t)N_NODES + col);
            }
}

extern "C" void kernel_launch(void* const* d_in, const int* in_sizes, int n_in,
                              void* d_out, int out_size, void* d_ws, size_t ws_size,
                              hipStream_t stream) {
    const float* X = (const float*)d_in[0];
    const int* edge = (const int*)d_in[1];
    const float* W1 = (const float*)d_in[2];
    const float* b1 = (const float*)d_in[3];
    const float* Wmu = (const float*)d_in[4];
    const float* bmu = (const float*)d_in[5];
    const float* Wsig = (const float*)d_in[6];
    const float* bsig = (const float*)d_in[7];
    const float* eps = (const float*)d_in[8];

    const int* esrc = edge;
    const int* edst = edge + N_EDGES;

    char* w = (char*)d_ws;
    int* deg = (int*)w;            w += (size_t)N_NODES * 4;
    int* cursor = (int*)w;         w += (size_t)N_NODES * 4;
    float* norm = (float*)w;       w += (size_t)N_NODES * 4;
    float* tvec = (float*)w;       w += (size_t)N_NODES * 4;
    int* rowptr = (int*)w;         w += (size_t)(N_NODES + 64) * 4;
    int* ssrc = (int*)w;           w += (size_t)N_EDGES * 4;
    unsigned short* Xb = (unsigned short*)w;   w += (size_t)N_NODES * DIN * 2;
    unsigned short* W1T = (unsigned short*)w;  w += (size_t)DIN * DH * 2;
    unsigned short* g1 = (unsigned short*)w;   w += (size_t)N_NODES * DH * 2;
    unsigned short* G2 = (unsigned short*)w;   w += (size_t)N_NODES * DH * 2;
    unsigned short* Zb = (unsigned short*)w;   w += (size_t)N_NODES * DZ * 2;

    float* out_zzt = (float*)d_out;
    float* out_mus = out_zzt + (size_t)N_NODES * N_NODES;
    float* out_logs = out_mus + (size_t)N_NODES * DZ;

    hipMemsetAsync(d_ws, 0, (size_t)N_NODES * 8, stream);  // deg + cursor
    k_prep<<<8192, 256, 0, stream>>>(X, Xb, W1, W1T, edst, deg);
    k_scan<<<1, 1024, 0, stream>>>(deg, rowptr, norm);
    k_scatter<<<N_EDGES / 256, 256, 0, stream>>>(esrc, edst, rowptr, cursor, ssrc);
    k_gemm1<<<dim3(N_NODES / 256, DH / 64), 256, 0, stream>>>(Xb, W1T, b1, norm, g1);
    k_agg1<<<N_NODES / 4, 256, 0, stream>>>(g1, rowptr, ssrc, norm, G2, tvec);
    k_agg2<<<N_NODES / 4, 256, 0, stream>>>(G2, rowptr, ssrc, norm, tvec, Wmu, bmu, Wsig, bsig, eps,
                                            out_mus, out_logs, Zb);
    k_zzt<<<dim3(N_NODES / 128, N_NODES / 128), 256, 0, stream>>>(Zb, out_zzt);
}

// Round 3
// 298.163 us; speedup vs baseline: 1.7002x; 1.3575x over previous
//
#include <hip/hip_runtime.h>

#define N_NODES 12288
#define N_EDGES 393216
#define DIN 512
#define DH 256
#define DZ 64

typedef __bf16 bf16x8 __attribute__((ext_vector_type(8)));
typedef float f32x4 __attribute__((ext_vector_type(4)));

static __device__ __forceinline__ unsigned short f2bf(float f) {
    unsigned int u = __float_as_uint(f);
    unsigned int r = (u + 0x7fffu + ((u >> 16) & 1u)) >> 16;
    return (unsigned short)r;
}
static __device__ __forceinline__ float bf2f(unsigned short u) {
    return __uint_as_float((unsigned int)u << 16);
}

// ---- prep: cvt X->bf16, W1->W1T bf16, Wmu->WmuT bf16, count degrees ----
__global__ __launch_bounds__(256) void k_prep(const float* __restrict__ X, unsigned short* __restrict__ Xb,
                                              const float* __restrict__ W1, unsigned short* __restrict__ W1T,
                                              const float* __restrict__ Wmu, unsigned short* __restrict__ WmuT,
                                              const int* __restrict__ dst, int* __restrict__ deg) {
    int b = blockIdx.x;
    if (b < 6144) {                       // X: 12288*512/4 float4
        int i = b * 256 + threadIdx.x;
        float4 v = ((const float4*)X)[i];
        ushort4 o;
        o.x = f2bf(v.x); o.y = f2bf(v.y); o.z = f2bf(v.z); o.w = f2bf(v.w);
        ((ushort4*)Xb)[i] = o;
    } else if (b < 6656) {                // W1T: 512*256, i = c*512+k
        int i = (b - 6144) * 256 + threadIdx.x;
        int c = i >> 9, k = i & 511;
        W1T[i] = f2bf(W1[k * DH + c]);
    } else if (b < 6720) {                // WmuT: 64*256, i = c*256+k
        int i = (b - 6656) * 256 + threadIdx.x;
        int c = i >> 8, k = i & 255;
        WmuT[i] = f2bf(Wmu[k * DZ + c]);
    } else {                              // degree count: 1536 blocks
        int e = (b - 6720) * 256 + threadIdx.x;
        atomicAdd(&deg[dst[e]], 1);
    }
}

// ---- scan (rowptr) + norm fused ----
__global__ __launch_bounds__(1024) void k_scan(const int* __restrict__ cnt, int* __restrict__ rp,
                                               float* __restrict__ norm) {
    __shared__ int sp[1024];
    int t = threadIdx.x;
    int base = t * 12;
    int loc[12];
    int s = 0;
#pragma unroll
    for (int j = 0; j < 12; ++j) {
        int c = cnt[base + j];
        norm[base + j] = rsqrtf((float)c + 1.0f);
        loc[j] = s; s += c;
    }
    sp[t] = s;
    __syncthreads();
    for (int off = 1; off < 1024; off <<= 1) {
        int v = (t >= off) ? sp[t - off] : 0;
        __syncthreads();
        sp[t] += v;
        __syncthreads();
    }
    int pre = (t == 0) ? 0 : sp[t - 1];
#pragma unroll
    for (int j = 0; j < 12; ++j) rp[base + j] = pre + loc[j];
    if (t == 1023) rp[N_NODES] = sp[1023];
}

__global__ __launch_bounds__(256) void k_scatter(const int* __restrict__ src, const int* __restrict__ dst,
                                                 const int* __restrict__ rp, int* __restrict__ cursor,
                                                 int* __restrict__ ssrc) {
    int e = blockIdx.x * 256 + threadIdx.x;
    int d = dst[e];
    int pos = atomicAdd(&cursor[d], 1);
    ssrc[rp[d] + pos] = src[e];
}

// ---- g1 = norm .* (X @ W1 + b1)  (bf16 MFMA, bf16 out) ----
__global__ __launch_bounds__(256) void k_gemm1(const unsigned short* __restrict__ Xb,
                                               const unsigned short* __restrict__ W1T,
                                               const float* __restrict__ b1, const float* __restrict__ norm,
                                               unsigned short* __restrict__ g1) {
    int wid = threadIdx.x >> 6;
    int lane = threadIdx.x & 63;
    int ln = lane & 15, kg = lane >> 4;
    int rb = blockIdx.x * 256 + wid * 64;
    int cb = blockIdx.y * 64;
    f32x4 acc[4][4] = {};
    const unsigned short* xa = Xb + (size_t)(rb + ln) * DIN + kg * 8;
    const unsigned short* wb = W1T + (size_t)(cb + ln) * DIN + kg * 8;
    for (int ks = 0; ks < 16; ++ks) {
        int k0 = ks * 32;
        bf16x8 a[4], b[4];
#pragma unroll
        for (int m = 0; m < 4; ++m) a[m] = *(const bf16x8*)(xa + (size_t)m * 16 * DIN + k0);
#pragma unroll
        for (int n = 0; n < 4; ++n) b[n] = *(const bf16x8*)(wb + (size_t)n * 16 * DIN + k0);
#pragma unroll
        for (int m = 0; m < 4; ++m)
#pragma unroll
            for (int n = 0; n < 4; ++n)
                acc[m][n] = __builtin_amdgcn_mfma_f32_16x16x32_bf16(a[m], b[n], acc[m][n], 0, 0, 0);
    }
#pragma unroll
    for (int m = 0; m < 4; ++m)
#pragma unroll
        for (int r = 0; r < 4; ++r) {
            int row = rb + m * 16 + kg * 4 + r;
            float ni = norm[row];
#pragma unroll
            for (int n = 0; n < 4; ++n) {
                int col = cb + n * 16 + ln;
                g1[(size_t)row * DH + col] = f2bf(ni * (acc[m][n][r] + b1[col]));
            }
        }
}

// ---- agg1: wave-per-node. G2 = norm .* relu(norm*(sum g1[src] + g1[i]))
//      also: tvec = sum norm[src]+norm[i];  qv = dot(G2[i], Wsig) ----
__global__ __launch_bounds__(256) void k_agg1(const unsigned short* __restrict__ g1,
                                              const int* __restrict__ rp, const int* __restrict__ ssrc,
                                              const float* __restrict__ norm, const float* __restrict__ Wsig,
                                              unsigned short* __restrict__ G2, float* __restrict__ tvec,
                                              float* __restrict__ qv) {
    int w = threadIdx.x >> 6;
    int lane = threadIdx.x & 63;
    int i = blockIdx.x * 4 + w;
    int beg = rp[i], end = rp[i + 1];
    float ax = 0.f, ay = 0.f, az = 0.f, aw = 0.f;
    float ssum = 0.f;
    int co = lane << 2;
#pragma unroll 2
    for (int e = beg; e < end; ++e) {
        int s = ssrc[e];
        ushort4 v = *(const ushort4*)(g1 + ((size_t)s << 8) + co);
        ssum += norm[s];
        ax += bf2f(v.x); ay += bf2f(v.y); az += bf2f(v.z); aw += bf2f(v.w);
    }
    ushort4 sv = *(const ushort4*)(g1 + ((size_t)i << 8) + co);
    ax += bf2f(sv.x); ay += bf2f(sv.y); az += bf2f(sv.z); aw += bf2f(sv.w);
    float ni = norm[i];
    float gx = ni * fmaxf(ni * ax, 0.f);
    float gy = ni * fmaxf(ni * ay, 0.f);
    float gz = ni * fmaxf(ni * az, 0.f);
    float gw = ni * fmaxf(ni * aw, 0.f);
    ushort4 o;
    o.x = f2bf(gx); o.y = f2bf(gy); o.z = f2bf(gz); o.w = f2bf(gw);
    *(ushort4*)(G2 + ((size_t)i << 8) + co) = o;
    // qv = dot(G2[i], Wsig) via butterfly
    const float4 wsg = *(const float4*)(Wsig + co);
    float qp = gx * wsg.x + gy * wsg.y + gz * wsg.z + gw * wsg.w;
#pragma unroll
    for (int m = 32; m >= 1; m >>= 1) qp += __shfl_xor(qp, m);
    // all lanes also reduce ssum
#pragma unroll
    for (int m = 32; m >= 1; m >>= 1) ssum += __shfl_xor(ssum, m);
    if (lane == 0) {
        tvec[i] = ssum / 64.f + ni;   // each lane summed same ssum? no: per-lane identical loop -> same value; /64 fixes butterfly sum
        qv[i] = qp;
    }
}

// ---- gemm2: P = G2 @ Wmu (bf16 MFMA, bf16 out), M=12288 K=256 N=64 ----
__global__ __launch_bounds__(256) void k_gemm2(const unsigned short* __restrict__ G2,
                                               const unsigned short* __restrict__ WmuT,
                                               unsigned short* __restrict__ Pb) {
    int wid = threadIdx.x >> 6;
    int lane = threadIdx.x & 63;
    int ln = lane & 15, kg = lane >> 4;
    int rb = blockIdx.x * 128 + wid * 32;
    f32x4 acc[2][4] = {};
    const unsigned short* xa = G2 + (size_t)(rb + ln) * DH + kg * 8;
    const unsigned short* wb = WmuT + (size_t)ln * DH + kg * 8;
    for (int ks = 0; ks < 8; ++ks) {
        int k0 = ks * 32;
        bf16x8 a[2], b[4];
#pragma unroll
        for (int m = 0; m < 2; ++m) a[m] = *(const bf16x8*)(xa + (size_t)m * 16 * DH + k0);
#pragma unroll
        for (int n = 0; n < 4; ++n) b[n] = *(const bf16x8*)(wb + (size_t)n * 16 * DH + k0);
#pragma unroll
        for (int m = 0; m < 2; ++m)
#pragma unroll
            for (int n = 0; n < 4; ++n)
                acc[m][n] = __builtin_amdgcn_mfma_f32_16x16x32_bf16(a[m], b[n], acc[m][n], 0, 0, 0);
    }
#pragma unroll
    for (int m = 0; m < 2; ++m)
#pragma unroll
        for (int n = 0; n < 4; ++n)
#pragma unroll
            for (int r = 0; r < 4; ++r) {
                int row = rb + m * 16 + kg * 4 + r;
                int col = n * 16 + ln;
                Pb[(size_t)row * DZ + col] = f2bf(acc[m][n][r]);
            }
}

// ---- agg2: wave-per-node, lane-per-latent-channel. No LDS, no shuffles. ----
__global__ __launch_bounds__(256) void k_agg2(const unsigned short* __restrict__ Pb,
                                              const float* __restrict__ qv,
                                              const int* __restrict__ rp, const int* __restrict__ ssrc,
                                              const float* __restrict__ norm, const float* __restrict__ tvec,
                                              const float* __restrict__ bmu, const float* __restrict__ bsig,
                                              const float* __restrict__ eps,
                                              float* __restrict__ mus_out, float* __restrict__ logs_out,
                                              unsigned short* __restrict__ Zb) {
    int w = threadIdx.x >> 6;
    int lane = threadIdx.x & 63;
    int i = blockIdx.x * 4 + w;
    int beg = rp[i], end = rp[i + 1];
    float acc = 0.f, qa = 0.f;
#pragma unroll 2
    for (int e = beg; e < end; ++e) {
        int s = ssrc[e];
        acc += bf2f(Pb[((size_t)s << 6) + lane]);
        qa += qv[s];
    }
    acc += bf2f(Pb[((size_t)i << 6) + lane]);
    qa += qv[i];
    float ni = norm[i], tv = tvec[i];
    float mu = ni * (acc + bmu[lane] * tv);
    float ls = ni * (qa + bsig[0] * tv);
    if (lane == 0) logs_out[i] = ls;
    float sig = expf(0.5f * ls);
    size_t oidx = ((size_t)i << 6) + lane;
    mus_out[oidx] = mu;
    Zb[oidx] = f2bf(mu + sig * eps[oidx]);
}

// ---- ZZt = Z @ Z^T (bf16 MFMA). Symmetric: store each tile TRANSPOSED so the
//      4 accumulator regs become 4 consecutive columns -> float4 NT stores. ----
__global__ __launch_bounds__(256) void k_zzt(const unsigned short* __restrict__ Zb, float* __restrict__ out) {
    int wid = threadIdx.x >> 6;
    int lane = threadIdx.x & 63;
    int ln = lane & 15, kg = lane >> 4;
    int rb = blockIdx.x * 128 + (wid >> 1) * 64;
    int cb = blockIdx.y * 128 + (wid & 1) * 64;
    bf16x8 a[4][2], b[4][2];
#pragma unroll
    for (int m = 0; m < 4; ++m)
#pragma unroll
        for (int kc = 0; kc < 2; ++kc)
            a[m][kc] = *(const bf16x8*)(Zb + (size_t)(rb + m * 16 + ln) * DZ + kc * 32 + kg * 8);
#pragma unroll
    for (int n = 0; n < 4; ++n)
#pragma unroll
        for (int kc = 0; kc < 2; ++kc)
            b[n][kc] = *(const bf16x8*)(Zb + (size_t)(cb + n * 16 + ln) * DZ + kc * 32 + kg * 8);
    f32x4 acc[4][4] = {};
#pragma unroll
    for (int m = 0; m < 4; ++m)
#pragma unroll
        for (int n = 0; n < 4; ++n) {
            acc[m][n] = __builtin_amdgcn_mfma_f32_16x16x32_bf16(a[m][0], b[n][0], acc[m][n], 0, 0, 0);
            acc[m][n] = __builtin_amdgcn_mfma_f32_16x16x32_bf16(a[m][1], b[n][1], acc[m][n], 0, 0, 0);
        }
    // transposed store: value dot(Z_row, Z_col) == dot(Z_col, Z_row) bitwise
#pragma unroll
    for (int m = 0; m < 4; ++m)
#pragma unroll
        for (int n = 0; n < 4; ++n) {
            size_t row = cb + n * 16 + ln;
            size_t col = rb + m * 16 + kg * 4;
            __builtin_nontemporal_store(acc[m][n], (f32x4*)(out + row * (size_t)N_NODES + col));
        }
}

extern "C" void kernel_launch(void* const* d_in, const int* in_sizes, int n_in,
                              void* d_out, int out_size, void* d_ws, size_t ws_size,
                              hipStream_t stream) {
    const float* X = (const float*)d_in[0];
    const int* edge = (const int*)d_in[1];
    const float* W1 = (const float*)d_in[2];
    const float* b1 = (const float*)d_in[3];
    const float* Wmu = (const float*)d_in[4];
    const float* bmu = (const float*)d_in[5];
    const float* Wsig = (const float*)d_in[6];
    const float* bsig = (const float*)d_in[7];
    const float* eps = (const float*)d_in[8];

    const int* esrc = edge;
    const int* edst = edge + N_EDGES;

    char* w = (char*)d_ws;
    int* deg = (int*)w;            w += (size_t)N_NODES * 4;
    int* cursor = (int*)w;         w += (size_t)N_NODES * 4;
    float* norm = (float*)w;       w += (size_t)N_NODES * 4;
    float* tvec = (float*)w;       w += (size_t)N_NODES * 4;
    float* qv = (float*)w;         w += (size_t)N_NODES * 4;
    int* rowptr = (int*)w;         w += (size_t)(N_NODES + 64) * 4;
    int* ssrc = (int*)w;           w += (size_t)N_EDGES * 4;
    unsigned short* Xb = (unsigned short*)w;   w += (size_t)N_NODES * DIN * 2;
    unsigned short* W1T = (unsigned short*)w;  w += (size_t)DIN * DH * 2;
    unsigned short* WmuT = (unsigned short*)w; w += (size_t)DH * DZ * 2;
    unsigned short* g1 = (unsigned short*)w;   w += (size_t)N_NODES * DH * 2;
    unsigned short* G2 = (unsigned short*)w;   w += (size_t)N_NODES * DH * 2;
    unsigned short* Pb = (unsigned short*)w;   w += (size_t)N_NODES * DZ * 2;
    unsigned short* Zb = (unsigned short*)w;   w += (size_t)N_NODES * DZ * 2;

    float* out_zzt = (float*)d_out;
    float* out_mus = out_zzt + (size_t)N_NODES * N_NODES;
    float* out_logs = out_mus + (size_t)N_NODES * DZ;

    hipMemsetAsync(d_ws, 0, (size_t)N_NODES * 8, stream);  // deg + cursor
    k_prep<<<8256, 256, 0, stream>>>(X, Xb, W1, W1T, Wmu, WmuT, edst, deg);
    k_scan<<<1, 1024, 0, stream>>>(deg, rowptr, norm);
    k_scatter<<<N_EDGES / 256, 256, 0, stream>>>(esrc, edst, rowptr, cursor, ssrc);
    k_gemm1<<<dim3(N_NODES / 256, DH / 64), 256, 0, stream>>>(Xb, W1T, b1, norm, g1);
    k_agg1<<<N_NODES / 4, 256, 0, stream>>>(g1, rowptr, ssrc, norm, Wsig, G2, tvec, qv);
    k_gemm2<<<N_NODES / 128, 256, 0, stream>>>(G2, WmuT, Pb);
    k_agg2<<<N_NODES / 4, 256, 0, stream>>>(Pb, qv, rowptr, ssrc, norm, tvec, bmu, bsig, eps,
                                            out_mus, out_logs, Zb);
    k_zzt<<<dim3(N_NODES / 128, N_NODES / 128), 256, 0, stream>>>(Zb, out_zzt);
}

// Round 4
// 282.769 us; speedup vs baseline: 1.7927x; 1.0544x over previous
//
#include <hip/hip_runtime.h>

#define N_NODES 12288
#define N_EDGES 393216
#define DIN 512
#define DH 256
#define DZ 64

typedef __bf16 bf16x8 __attribute__((ext_vector_type(8)));
typedef float f32x4 __attribute__((ext_vector_type(4)));

static __device__ __forceinline__ unsigned short f2bf(float f) {
    unsigned int u = __float_as_uint(f);
    unsigned int r = (u + 0x7fffu + ((u >> 16) & 1u)) >> 16;
    return (unsigned short)r;
}
static __device__ __forceinline__ float bf2f(unsigned short u) {
    return __uint_as_float((unsigned int)u << 16);
}

// ---- prep: cvt X->bf16, W1->W1T bf16, Wmu->WmuT bf16, count degrees ----
__global__ __launch_bounds__(256) void k_prep(const float* __restrict__ X, unsigned short* __restrict__ Xb,
                                              const float* __restrict__ W1, unsigned short* __restrict__ W1T,
                                              const float* __restrict__ Wmu, unsigned short* __restrict__ WmuT,
                                              const int* __restrict__ dst, int* __restrict__ deg) {
    int b = blockIdx.x;
    if (b < 6144) {                       // X: 12288*512/4 float4
        int i = b * 256 + threadIdx.x;
        float4 v = ((const float4*)X)[i];
        ushort4 o;
        o.x = f2bf(v.x); o.y = f2bf(v.y); o.z = f2bf(v.z); o.w = f2bf(v.w);
        ((ushort4*)Xb)[i] = o;
    } else if (b < 6656) {                // W1T: 512*256, i = c*512+k
        int i = (b - 6144) * 256 + threadIdx.x;
        int c = i >> 9, k = i & 511;
        W1T[i] = f2bf(W1[k * DH + c]);
    } else if (b < 6720) {                // WmuT: 64*256, i = c*256+k
        int i = (b - 6656) * 256 + threadIdx.x;
        int c = i >> 8, k = i & 255;
        WmuT[i] = f2bf(Wmu[k * DZ + c]);
    } else {                              // degree count: 1536 blocks
        int e = (b - 6720) * 256 + threadIdx.x;
        atomicAdd(&deg[dst[e]], 1);
    }
}

// ---- scan (rowptr) + norm fused ----
__global__ __launch_bounds__(1024) void k_scan(const int* __restrict__ cnt, int* __restrict__ rp,
                                               float* __restrict__ norm) {
    __shared__ int sp[1024];
    int t = threadIdx.x;
    int base = t * 12;
    int loc[12];
    int s = 0;
#pragma unroll
    for (int j = 0; j < 12; ++j) {
        int c = cnt[base + j];
        norm[base + j] = rsqrtf((float)c + 1.0f);
        loc[j] = s; s += c;
    }
    sp[t] = s;
    __syncthreads();
    for (int off = 1; off < 1024; off <<= 1) {
        int v = (t >= off) ? sp[t - off] : 0;
        __syncthreads();
        sp[t] += v;
        __syncthreads();
    }
    int pre = (t == 0) ? 0 : sp[t - 1];
#pragma unroll
    for (int j = 0; j < 12; ++j) rp[base + j] = pre + loc[j];
    if (t == 1023) rp[N_NODES] = sp[1023];
}

__global__ __launch_bounds__(256) void k_scatter(const int* __restrict__ src, const int* __restrict__ dst,
                                                 const int* __restrict__ rp, int* __restrict__ cursor,
                                                 int* __restrict__ ssrc) {
    int e = blockIdx.x * 256 + threadIdx.x;
    int d = dst[e];
    int pos = atomicAdd(&cursor[d], 1);
    ssrc[rp[d] + pos] = src[e];
}

// ---- g1 = norm .* (X @ W1 + b1)  (bf16 MFMA, bf16 out) ----
__global__ __launch_bounds__(256) void k_gemm1(const unsigned short* __restrict__ Xb,
                                               const unsigned short* __restrict__ W1T,
                                               const float* __restrict__ b1, const float* __restrict__ norm,
                                               unsigned short* __restrict__ g1) {
    int wid = threadIdx.x >> 6;
    int lane = threadIdx.x & 63;
    int ln = lane & 15, kg = lane >> 4;
    int rb = blockIdx.x * 256 + wid * 64;
    int cb = blockIdx.y * 64;
    f32x4 acc[4][4] = {};
    const unsigned short* xa = Xb + (size_t)(rb + ln) * DIN + kg * 8;
    const unsigned short* wb = W1T + (size_t)(cb + ln) * DIN + kg * 8;
    for (int ks = 0; ks < 16; ++ks) {
        int k0 = ks * 32;
        bf16x8 a[4], b[4];
#pragma unroll
        for (int m = 0; m < 4; ++m) a[m] = *(const bf16x8*)(xa + (size_t)m * 16 * DIN + k0);
#pragma unroll
        for (int n = 0; n < 4; ++n) b[n] = *(const bf16x8*)(wb + (size_t)n * 16 * DIN + k0);
#pragma unroll
        for (int m = 0; m < 4; ++m)
#pragma unroll
            for (int n = 0; n < 4; ++n)
                acc[m][n] = __builtin_amdgcn_mfma_f32_16x16x32_bf16(a[m], b[n], acc[m][n], 0, 0, 0);
    }
#pragma unroll
    for (int m = 0; m < 4; ++m)
#pragma unroll
        for (int r = 0; r < 4; ++r) {
            int row = rb + m * 16 + kg * 4 + r;
            float ni = norm[row];
#pragma unroll
            for (int n = 0; n < 4; ++n) {
                int col = cb + n * 16 + ln;
                g1[(size_t)row * DH + col] = f2bf(ni * (acc[m][n][r] + b1[col]));
            }
        }
}

// ---- agg1: wave-per-node. G2 = norm .* relu(norm*(sum g1[src] + g1[i]))
//      also: tvec = sum norm[src]+norm[i];  qv = dot(G2[i], Wsig) ----
__global__ __launch_bounds__(256) void k_agg1(const unsigned short* __restrict__ g1,
                                              const int* __restrict__ rp, const int* __restrict__ ssrc,
                                              const float* __restrict__ norm, const float* __restrict__ Wsig,
                                              unsigned short* __restrict__ G2, float* __restrict__ tvec,
                                              float* __restrict__ qv) {
    int w = threadIdx.x >> 6;
    int lane = threadIdx.x & 63;
    int i = blockIdx.x * 4 + w;
    int beg = rp[i], end = rp[i + 1];
    float ax = 0.f, ay = 0.f, az = 0.f, aw = 0.f;
    float ssum = 0.f;
    int co = lane << 2;
#pragma unroll 2
    for (int e = beg; e < end; ++e) {
        int s = ssrc[e];
        ushort4 v = *(const ushort4*)(g1 + ((size_t)s << 8) + co);
        ssum += norm[s];
        ax += bf2f(v.x); ay += bf2f(v.y); az += bf2f(v.z); aw += bf2f(v.w);
    }
    ushort4 sv = *(const ushort4*)(g1 + ((size_t)i << 8) + co);
    ax += bf2f(sv.x); ay += bf2f(sv.y); az += bf2f(sv.z); aw += bf2f(sv.w);
    float ni = norm[i];
    float gx = ni * fmaxf(ni * ax, 0.f);
    float gy = ni * fmaxf(ni * ay, 0.f);
    float gz = ni * fmaxf(ni * az, 0.f);
    float gw = ni * fmaxf(ni * aw, 0.f);
    ushort4 o;
    o.x = f2bf(gx); o.y = f2bf(gy); o.z = f2bf(gz); o.w = f2bf(gw);
    *(ushort4*)(G2 + ((size_t)i << 8) + co) = o;
    // qv = dot(G2[i], Wsig) via butterfly
    const float4 wsg = *(const float4*)(Wsig + co);
    float qp = gx * wsg.x + gy * wsg.y + gz * wsg.z + gw * wsg.w;
#pragma unroll
    for (int m = 32; m >= 1; m >>= 1) qp += __shfl_xor(qp, m);
#pragma unroll
    for (int m = 32; m >= 1; m >>= 1) ssum += __shfl_xor(ssum, m);
    if (lane == 0) {
        tvec[i] = ssum / 64.f + ni;   // per-lane ssum identical; butterfly multiplied by 64
        qv[i] = qp;
    }
}

// ---- gemm2: P = G2 @ Wmu (bf16 MFMA, bf16 out), M=12288 K=256 N=64 ----
__global__ __launch_bounds__(256) void k_gemm2(const unsigned short* __restrict__ G2,
                                               const unsigned short* __restrict__ WmuT,
                                               unsigned short* __restrict__ Pb) {
    int wid = threadIdx.x >> 6;
    int lane = threadIdx.x & 63;
    int ln = lane & 15, kg = lane >> 4;
    int rb = blockIdx.x * 128 + wid * 32;
    f32x4 acc[2][4] = {};
    const unsigned short* xa = G2 + (size_t)(rb + ln) * DH + kg * 8;
    const unsigned short* wb = WmuT + (size_t)ln * DH + kg * 8;
    for (int ks = 0; ks < 8; ++ks) {
        int k0 = ks * 32;
        bf16x8 a[2], b[4];
#pragma unroll
        for (int m = 0; m < 2; ++m) a[m] = *(const bf16x8*)(xa + (size_t)m * 16 * DH + k0);
#pragma unroll
        for (int n = 0; n < 4; ++n) b[n] = *(const bf16x8*)(wb + (size_t)n * 16 * DH + k0);
#pragma unroll
        for (int m = 0; m < 2; ++m)
#pragma unroll
            for (int n = 0; n < 4; ++n)
                acc[m][n] = __builtin_amdgcn_mfma_f32_16x16x32_bf16(a[m], b[n], acc[m][n], 0, 0, 0);
    }
#pragma unroll
    for (int m = 0; m < 2; ++m)
#pragma unroll
        for (int n = 0; n < 4; ++n)
#pragma unroll
            for (int r = 0; r < 4; ++r) {
                int row = rb + m * 16 + kg * 4 + r;
                int col = n * 16 + ln;
                Pb[(size_t)row * DZ + col] = f2bf(acc[m][n][r]);
            }
}

// ---- agg2: wave-per-node, lane-per-latent-channel. ----
__global__ __launch_bounds__(256) void k_agg2(const unsigned short* __restrict__ Pb,
                                              const float* __restrict__ qv,
                                              const int* __restrict__ rp, const int* __restrict__ ssrc,
                                              const float* __restrict__ norm, const float* __restrict__ tvec,
                                              const float* __restrict__ bmu, const float* __restrict__ bsig,
                                              const float* __restrict__ eps,
                                              float* __restrict__ mus_out, float* __restrict__ logs_out,
                                              unsigned short* __restrict__ Zb) {
    int w = threadIdx.x >> 6;
    int lane = threadIdx.x & 63;
    int i = blockIdx.x * 4 + w;
    int beg = rp[i], end = rp[i + 1];
    float acc = 0.f, qa = 0.f;
#pragma unroll 2
    for (int e = beg; e < end; ++e) {
        int s = ssrc[e];
        acc += bf2f(Pb[((size_t)s << 6) + lane]);
        qa += qv[s];
    }
    acc += bf2f(Pb[((size_t)i << 6) + lane]);
    qa += qv[i];
    float ni = norm[i], tv = tvec[i];
    float mu = ni * (acc + bmu[lane] * tv);
    float ls = ni * (qa + bsig[0] * tv);
    if (lane == 0) logs_out[i] = ls;
    float sig = expf(0.5f * ls);
    size_t oidx = ((size_t)i << 6) + lane;
    mus_out[oidx] = mu;
    Zb[oidx] = f2bf(mu + sig * eps[oidx]);
}

// ---- ZZt = Z @ Z^T. 64x256 tile, LDS-staged epilogue, full-line NT stores. ----
#define LPAD 260
__global__ __launch_bounds__(256) void k_zzt(const unsigned short* __restrict__ Zb, float* __restrict__ out) {
    __shared__ float lds[64 * LPAD];
    int w = threadIdx.x >> 6;
    int lane = threadIdx.x & 63;
    int ln = lane & 15, kg = lane >> 4;
    int rb = blockIdx.x * 64;           // output rows
    int cb = blockIdx.y * 256 + w * 64; // output cols, wave-split
    bf16x8 a[4][2], b[4][2];
#pragma unroll
    for (int m = 0; m < 4; ++m)
#pragma unroll
        for (int kc = 0; kc < 2; ++kc)
            a[m][kc] = *(const bf16x8*)(Zb + (size_t)(rb + m * 16 + ln) * DZ + kc * 32 + kg * 8);
#pragma unroll
    for (int n = 0; n < 4; ++n)
#pragma unroll
        for (int kc = 0; kc < 2; ++kc)
            b[n][kc] = *(const bf16x8*)(Zb + (size_t)(cb + n * 16 + ln) * DZ + kc * 32 + kg * 8);
    f32x4 acc[4][4] = {};
#pragma unroll
    for (int m = 0; m < 4; ++m)
#pragma unroll
        for (int n = 0; n < 4; ++n) {
            acc[m][n] = __builtin_amdgcn_mfma_f32_16x16x32_bf16(a[m][0], b[n][0], acc[m][n], 0, 0, 0);
            acc[m][n] = __builtin_amdgcn_mfma_f32_16x16x32_bf16(a[m][1], b[n][1], acc[m][n], 0, 0, 0);
        }
    // stage to LDS: row = m*16+kg*4+r (0..63), col = w*64 + n*16 + ln (0..255)
#pragma unroll
    for (int m = 0; m < 4; ++m)
#pragma unroll
        for (int n = 0; n < 4; ++n)
#pragma unroll
            for (int r = 0; r < 4; ++r)
                lds[(m * 16 + kg * 4 + r) * LPAD + w * 64 + n * 16 + ln] = acc[m][n][r];
    __syncthreads();
    // cooperative store: each wave stores one full 1024B row-run per instruction
    int c4 = (threadIdx.x & 63) * 4;
    int rw = threadIdx.x >> 6;
    size_t colbase = (size_t)blockIdx.y * 256 + c4;
#pragma unroll
    for (int it = 0; it < 16; ++it) {
        int row = it * 4 + rw;
        f32x4 v = *(const f32x4*)&lds[row * LPAD + c4];
        __builtin_nontemporal_store(v, (f32x4*)(out + (size_t)(rb + row) * N_NODES + colbase));
    }
}

extern "C" void kernel_launch(void* const* d_in, const int* in_sizes, int n_in,
                              void* d_out, int out_size, void* d_ws, size_t ws_size,
                              hipStream_t stream) {
    const float* X = (const float*)d_in[0];
    const int* edge = (const int*)d_in[1];
    const float* W1 = (const float*)d_in[2];
    const float* b1 = (const float*)d_in[3];
    const float* Wmu = (const float*)d_in[4];
    const float* bmu = (const float*)d_in[5];
    const float* Wsig = (const float*)d_in[6];
    const float* bsig = (const float*)d_in[7];
    const float* eps = (const float*)d_in[8];

    const int* esrc = edge;
    const int* edst = edge + N_EDGES;

    char* w = (char*)d_ws;
    int* deg = (int*)w;            w += (size_t)N_NODES * 4;
    int* cursor = (int*)w;         w += (size_t)N_NODES * 4;
    float* norm = (float*)w;       w += (size_t)N_NODES * 4;
    float* tvec = (float*)w;       w += (size_t)N_NODES * 4;
    float* qv = (float*)w;         w += (size_t)N_NODES * 4;
    int* rowptr = (int*)w;         w += (size_t)(N_NODES + 64) * 4;
    int* ssrc = (int*)w;           w += (size_t)N_EDGES * 4;
    unsigned short* Xb = (unsigned short*)w;   w += (size_t)N_NODES * DIN * 2;
    unsigned short* W1T = (unsigned short*)w;  w += (size_t)DIN * DH * 2;
    unsigned short* WmuT = (unsigned short*)w; w += (size_t)DH * DZ * 2;
    unsigned short* g1 = (unsigned short*)w;   w += (size_t)N_NODES * DH * 2;
    unsigned short* G2 = (unsigned short*)w;   w += (size_t)N_NODES * DH * 2;
    unsigned short* Pb = (unsigned short*)w;   w += (size_t)N_NODES * DZ * 2;
    unsigned short* Zb = (unsigned short*)w;   w += (size_t)N_NODES * DZ * 2;

    float* out_zzt = (float*)d_out;
    float* out_mus = out_zzt + (size_t)N_NODES * N_NODES;
    float* out_logs = out_mus + (size_t)N_NODES * DZ;

    hipMemsetAsync(d_ws, 0, (size_t)N_NODES * 8, stream);  // deg + cursor
    k_prep<<<8256, 256, 0, stream>>>(X, Xb, W1, W1T, Wmu, WmuT, edst, deg);
    k_scan<<<1, 1024, 0, stream>>>(deg, rowptr, norm);
    k_scatter<<<N_EDGES / 256, 256, 0, stream>>>(esrc, edst, rowptr, cursor, ssrc);
    k_gemm1<<<dim3(N_NODES / 256, DH / 64), 256, 0, stream>>>(Xb, W1T, b1, norm, g1);
    k_agg1<<<N_NODES / 4, 256, 0, stream>>>(g1, rowptr, ssrc, norm, Wsig, G2, tvec, qv);
    k_gemm2<<<N_NODES / 128, 256, 0, stream>>>(G2, WmuT, Pb);
    k_agg2<<<N_NODES / 4, 256, 0, stream>>>(Pb, qv, rowptr, ssrc, norm, tvec, bmu, bsig, eps,
                                            out_mus, out_logs, Zb);
    k_zzt<<<dim3(N_NODES / 64, N_NODES / 256), 256, 0, stream>>>(Zb, out_zzt);
}

// Round 5
// 278.444 us; speedup vs baseline: 1.8206x; 1.0155x over previous
//
#include <hip/hip_runtime.h>

#define N_NODES 12288
#define N_EDGES 393216
#define DIN 512
#define DH 256
#define DZ 64

typedef __bf16 bf16x8 __attribute__((ext_vector_type(8)));
typedef float f32x4 __attribute__((ext_vector_type(4)));
typedef unsigned short u16x8 __attribute__((ext_vector_type(8)));

static __device__ __forceinline__ unsigned short f2bf(float f) {
    unsigned int u = __float_as_uint(f);
    unsigned int r = (u + 0x7fffu + ((u >> 16) & 1u)) >> 16;
    return (unsigned short)r;
}
static __device__ __forceinline__ float bf2f(unsigned short u) {
    return __uint_as_float((unsigned int)u << 16);
}

// ---- prep: cvt X->bf16, W1->W1T bf16, Wmu->WmuT bf16, count degrees ----
__global__ __launch_bounds__(256) void k_prep(const float* __restrict__ X, unsigned short* __restrict__ Xb,
                                              const float* __restrict__ W1, unsigned short* __restrict__ W1T,
                                              const float* __restrict__ Wmu, unsigned short* __restrict__ WmuT,
                                              const int* __restrict__ dst, int* __restrict__ deg) {
    int b = blockIdx.x;
    if (b < 6144) {                       // X: 12288*512/4 float4
        int i = b * 256 + threadIdx.x;
        float4 v = ((const float4*)X)[i];
        ushort4 o;
        o.x = f2bf(v.x); o.y = f2bf(v.y); o.z = f2bf(v.z); o.w = f2bf(v.w);
        ((ushort4*)Xb)[i] = o;
    } else if (b < 6656) {                // W1T: 512*256, i = c*512+k
        int i = (b - 6144) * 256 + threadIdx.x;
        int c = i >> 9, k = i & 511;
        W1T[i] = f2bf(W1[k * DH + c]);
    } else if (b < 6720) {                // WmuT: 64*256, i = c*256+k
        int i = (b - 6656) * 256 + threadIdx.x;
        int c = i >> 8, k = i & 255;
        WmuT[i] = f2bf(Wmu[k * DZ + c]);
    } else {                              // degree count: 1536 blocks
        int e = (b - 6720) * 256 + threadIdx.x;
        atomicAdd(&deg[dst[e]], 1);
    }
}

// ---- scan (rowptr) + norm fused ----
__global__ __launch_bounds__(1024) void k_scan(const int* __restrict__ cnt, int* __restrict__ rp,
                                               float* __restrict__ norm) {
    __shared__ int sp[1024];
    int t = threadIdx.x;
    int base = t * 12;
    int loc[12];
    int s = 0;
#pragma unroll
    for (int j = 0; j < 12; ++j) {
        int c = cnt[base + j];
        norm[base + j] = rsqrtf((float)c + 1.0f);
        loc[j] = s; s += c;
    }
    sp[t] = s;
    __syncthreads();
    for (int off = 1; off < 1024; off <<= 1) {
        int v = (t >= off) ? sp[t - off] : 0;
        __syncthreads();
        sp[t] += v;
        __syncthreads();
    }
    int pre = (t == 0) ? 0 : sp[t - 1];
#pragma unroll
    for (int j = 0; j < 12; ++j) rp[base + j] = pre + loc[j];
    if (t == 1023) rp[N_NODES] = sp[1023];
}

__global__ __launch_bounds__(256) void k_scatter(const int* __restrict__ src, const int* __restrict__ dst,
                                                 const int* __restrict__ rp, int* __restrict__ cursor,
                                                 int* __restrict__ ssrc) {
    int e = blockIdx.x * 256 + threadIdx.x;
    int d = dst[e];
    int pos = atomicAdd(&cursor[d], 1);
    ssrc[rp[d] + pos] = src[e];
}

// ---- g1 = norm .* (X @ W1 + b1)  (bf16 MFMA, bf16 out). 512 thr, 2 col panels. ----
__global__ __launch_bounds__(512) void k_gemm1(const unsigned short* __restrict__ Xb,
                                               const unsigned short* __restrict__ W1T,
                                               const float* __restrict__ b1, const float* __restrict__ norm,
                                               unsigned short* __restrict__ g1) {
    int wid = threadIdx.x >> 6;
    int lane = threadIdx.x & 63;
    int ln = lane & 15, kg = lane >> 4;
    int rb = blockIdx.x * 256 + (wid >> 1) * 64;
    int cb = blockIdx.y * 128 + (wid & 1) * 64;
    f32x4 acc[4][4] = {};
    const unsigned short* xa = Xb + (size_t)(rb + ln) * DIN + kg * 8;
    const unsigned short* wb = W1T + (size_t)(cb + ln) * DIN + kg * 8;
    for (int ks = 0; ks < 16; ++ks) {
        int k0 = ks * 32;
        bf16x8 a[4], b[4];
#pragma unroll
        for (int m = 0; m < 4; ++m) a[m] = *(const bf16x8*)(xa + (size_t)m * 16 * DIN + k0);
#pragma unroll
        for (int n = 0; n < 4; ++n) b[n] = *(const bf16x8*)(wb + (size_t)n * 16 * DIN + k0);
#pragma unroll
        for (int m = 0; m < 4; ++m)
#pragma unroll
            for (int n = 0; n < 4; ++n)
                acc[m][n] = __builtin_amdgcn_mfma_f32_16x16x32_bf16(a[m], b[n], acc[m][n], 0, 0, 0);
    }
#pragma unroll
    for (int m = 0; m < 4; ++m)
#pragma unroll
        for (int r = 0; r < 4; ++r) {
            int row = rb + m * 16 + kg * 4 + r;
            float ni = norm[row];
#pragma unroll
            for (int n = 0; n < 4; ++n) {
                int col = cb + n * 16 + ln;
                g1[(size_t)row * DH + col] = f2bf(ni * (acc[m][n][r] + b1[col]));
            }
        }
}

// ---- agg1: wave-per-node, 2 edges/instruction (half-wave x ushort8).
//      G2 = norm .* relu(norm*(sum g1[src] + g1[i])); tvec; qv = dot(G2[i],Wsig) ----
__global__ __launch_bounds__(256) void k_agg1(const unsigned short* __restrict__ g1,
                                              const int* __restrict__ rp, const int* __restrict__ ssrc,
                                              const float* __restrict__ norm, const float* __restrict__ Wsig,
                                              unsigned short* __restrict__ G2, float* __restrict__ tvec,
                                              float* __restrict__ qv) {
    int w = threadIdx.x >> 6;
    int lane = threadIdx.x & 63;
    int half = lane >> 5, lh = lane & 31;
    int i = blockIdx.x * 4 + w;
    int beg = rp[i], end = rp[i + 1];
    int cnt = end - beg;
    int itn = (cnt + 1) >> 1;
    size_t cho = (size_t)lh * 8;
    float a8[8] = {};
    float ssum = 0.f;
#pragma unroll 2
    for (int it = 0; it < itn; ++it) {
        int e = beg + it * 2 + half;
        if (e < end) {
            int s = ssrc[e];
            u16x8 v = *(const u16x8*)(g1 + ((size_t)s << 8) + cho);
            ssum += norm[s];
#pragma unroll
            for (int j = 0; j < 8; ++j) a8[j] += bf2f(v[j]);
        }
    }
    if (half == 0) {   // self-loop once
        u16x8 v = *(const u16x8*)(g1 + ((size_t)i << 8) + cho);
#pragma unroll
        for (int j = 0; j < 8; ++j) a8[j] += bf2f(v[j]);
    }
#pragma unroll
    for (int j = 0; j < 8; ++j) a8[j] += __shfl_xor(a8[j], 32);
    ssum += __shfl_xor(ssum, 32);
    float ni = norm[i];
    const float4 ws0 = *(const float4*)(Wsig + cho);
    const float4 ws1 = *(const float4*)(Wsig + cho + 4);
    float g[8];
#pragma unroll
    for (int j = 0; j < 8; ++j) g[j] = ni * fmaxf(ni * a8[j], 0.f);
    float qp = g[0] * ws0.x + g[1] * ws0.y + g[2] * ws0.z + g[3] * ws0.w
             + g[4] * ws1.x + g[5] * ws1.y + g[6] * ws1.z + g[7] * ws1.w;
    if (half == 0) {
        u16x8 o;
#pragma unroll
        for (int j = 0; j < 8; ++j) o[j] = f2bf(g[j]);
        *(u16x8*)(G2 + ((size_t)i << 8) + cho) = o;
    }
#pragma unroll
    for (int m = 16; m >= 1; m >>= 1) qp += __shfl_xor(qp, m);
    if (lane == 0) {
        tvec[i] = ssum + ni;
        qv[i] = qp;
    }
}

// ---- gemm2: P = G2 @ Wmu (bf16 MFMA, bf16 out), M=12288 K=256 N=64 ----
__global__ __launch_bounds__(256) void k_gemm2(const unsigned short* __restrict__ G2,
                                               const unsigned short* __restrict__ WmuT,
                                               unsigned short* __restrict__ Pb) {
    int wid = threadIdx.x >> 6;
    int lane = threadIdx.x & 63;
    int ln = lane & 15, kg = lane >> 4;
    int rb = blockIdx.x * 128 + wid * 32;
    f32x4 acc[2][4] = {};
    const unsigned short* xa = G2 + (size_t)(rb + ln) * DH + kg * 8;
    const unsigned short* wb = WmuT + (size_t)ln * DH + kg * 8;
    for (int ks = 0; ks < 8; ++ks) {
        int k0 = ks * 32;
        bf16x8 a[2], b[4];
#pragma unroll
        for (int m = 0; m < 2; ++m) a[m] = *(const bf16x8*)(xa + (size_t)m * 16 * DH + k0);
#pragma unroll
        for (int n = 0; n < 4; ++n) b[n] = *(const bf16x8*)(wb + (size_t)n * 16 * DH + k0);
#pragma unroll
        for (int m = 0; m < 2; ++m)
#pragma unroll
            for (int n = 0; n < 4; ++n)
                acc[m][n] = __builtin_amdgcn_mfma_f32_16x16x32_bf16(a[m], b[n], acc[m][n], 0, 0, 0);
    }
#pragma unroll
    for (int m = 0; m < 2; ++m)
#pragma unroll
        for (int n = 0; n < 4; ++n)
#pragma unroll
            for (int r = 0; r < 4; ++r) {
                int row = rb + m * 16 + kg * 4 + r;
                int col = n * 16 + ln;
                Pb[(size_t)row * DZ + col] = f2bf(acc[m][n][r]);
            }
}

// ---- agg2: wave-per-node, 4 edges/iteration (16-lane groups x ushort4). ----
__global__ __launch_bounds__(256) void k_agg2(const unsigned short* __restrict__ Pb,
                                              const float* __restrict__ qv,
                                              const int* __restrict__ rp, const int* __restrict__ ssrc,
                                              const float* __restrict__ norm, const float* __restrict__ tvec,
                                              const float* __restrict__ bmu, const float* __restrict__ bsig,
                                              const float* __restrict__ eps,
                                              float* __restrict__ mus_out, float* __restrict__ logs_out,
                                              unsigned short* __restrict__ Zb) {
    int w = threadIdx.x >> 6;
    int lane = threadIdx.x & 63;
    int grp = lane >> 4, li = lane & 15;
    int i = blockIdx.x * 4 + w;
    int beg = rp[i], end = rp[i + 1];
    int cnt = end - beg;
    int itn = (cnt + 3) >> 2;
    int co = li * 4;
    float a4[4] = {};
    float qa = 0.f;
#pragma unroll 2
    for (int it = 0; it < itn; ++it) {
        int e = beg + it * 4 + grp;
        if (e < end) {
            int s = ssrc[e];
            ushort4 v = *(const ushort4*)(Pb + ((size_t)s << 6) + co);
            qa += qv[s];
            a4[0] += bf2f(v.x); a4[1] += bf2f(v.y); a4[2] += bf2f(v.z); a4[3] += bf2f(v.w);
        }
    }
    if (grp == 0) {   // self-loop
        ushort4 v = *(const ushort4*)(Pb + ((size_t)i << 6) + co);
        qa += qv[i];
        a4[0] += bf2f(v.x); a4[1] += bf2f(v.y); a4[2] += bf2f(v.z); a4[3] += bf2f(v.w);
    }
#pragma unroll
    for (int j = 0; j < 4; ++j) {
        a4[j] += __shfl_xor(a4[j], 16);
        a4[j] += __shfl_xor(a4[j], 32);
    }
    qa += __shfl_xor(qa, 16);
    qa += __shfl_xor(qa, 32);
    float ni = norm[i], tv = tvec[i];
    float ls = ni * (qa + bsig[0] * tv);
    float sig = expf(0.5f * ls);
    if (lane == 0) logs_out[i] = ls;
    if (lane < 16) {
        const float4 bm = *(const float4*)(bmu + co);
        float4 mu;
        mu.x = ni * (a4[0] + bm.x * tv);
        mu.y = ni * (a4[1] + bm.y * tv);
        mu.z = ni * (a4[2] + bm.z * tv);
        mu.w = ni * (a4[3] + bm.w * tv);
        size_t oidx = ((size_t)i << 6) + co;
        *(float4*)(mus_out + oidx) = mu;
        const float4 ep = *(const float4*)(eps + oidx);
        ushort4 z;
        z.x = f2bf(mu.x + sig * ep.x);
        z.y = f2bf(mu.y + sig * ep.y);
        z.z = f2bf(mu.z + sig * ep.z);
        z.w = f2bf(mu.w + sig * ep.w);
        *(ushort4*)(Zb + oidx) = z;
    }
}

// ---- ZZt = Z @ Z^T. 64x256 tile, 2-phase LDS epilogue (33KB -> more blocks/CU). ----
#define LPAD 260
__global__ __launch_bounds__(256) void k_zzt(const unsigned short* __restrict__ Zb, float* __restrict__ out) {
    __shared__ float lds[32 * LPAD];
    int w = threadIdx.x >> 6;
    int lane = threadIdx.x & 63;
    int ln = lane & 15, kg = lane >> 4;
    int rb = blockIdx.x * 64;           // output rows
    int cb = blockIdx.y * 256 + w * 64; // output cols, wave-split
    bf16x8 a[4][2], b[4][2];
#pragma unroll
    for (int m = 0; m < 4; ++m)
#pragma unroll
        for (int kc = 0; kc < 2; ++kc)
            a[m][kc] = *(const bf16x8*)(Zb + (size_t)(rb + m * 16 + ln) * DZ + kc * 32 + kg * 8);
#pragma unroll
    for (int n = 0; n < 4; ++n)
#pragma unroll
        for (int kc = 0; kc < 2; ++kc)
            b[n][kc] = *(const bf16x8*)(Zb + (size_t)(cb + n * 16 + ln) * DZ + kc * 32 + kg * 8);
    f32x4 acc[4][4] = {};
#pragma unroll
    for (int m = 0; m < 4; ++m)
#pragma unroll
        for (int n = 0; n < 4; ++n) {
            acc[m][n] = __builtin_amdgcn_mfma_f32_16x16x32_bf16(a[m][0], b[n][0], acc[m][n], 0, 0, 0);
            acc[m][n] = __builtin_amdgcn_mfma_f32_16x16x32_bf16(a[m][1], b[n][1], acc[m][n], 0, 0, 0);
        }
    int c4 = (threadIdx.x & 63) * 4;
    int rw = threadIdx.x >> 6;
    size_t colbase = (size_t)blockIdx.y * 256 + c4;
#pragma unroll
    for (int p = 0; p < 2; ++p) {
        if (p) __syncthreads();          // stores of phase 0 done reading LDS
#pragma unroll
        for (int mm = 0; mm < 2; ++mm) {
            int m = p * 2 + mm;
#pragma unroll
            for (int n = 0; n < 4; ++n)
#pragma unroll
                for (int r = 0; r < 4; ++r)
                    lds[(mm * 16 + kg * 4 + r) * LPAD + w * 64 + n * 16 + ln] = acc[m][n][r];
        }
        __syncthreads();
#pragma unroll
        for (int it = 0; it < 8; ++it) {
            int rl = it * 4 + rw;
            f32x4 v = *(const f32x4*)&lds[rl * LPAD + c4];
            __builtin_nontemporal_store(v, (f32x4*)(out + (size_t)(rb + p * 32 + rl) * N_NODES + colbase));
        }
    }
}

extern "C" void kernel_launch(void* const* d_in, const int* in_sizes, int n_in,
                              void* d_out, int out_size, void* d_ws, size_t ws_size,
                              hipStream_t stream) {
    const float* X = (const float*)d_in[0];
    const int* edge = (const int*)d_in[1];
    const float* W1 = (const float*)d_in[2];
    const float* b1 = (const float*)d_in[3];
    const float* Wmu = (const float*)d_in[4];
    const float* bmu = (const float*)d_in[5];
    const float* Wsig = (const float*)d_in[6];
    const float* bsig = (const float*)d_in[7];
    const float* eps = (const float*)d_in[8];

    const int* esrc = edge;
    const int* edst = edge + N_EDGES;

    char* w = (char*)d_ws;
    int* deg = (int*)w;            w += (size_t)N_NODES * 4;
    int* cursor = (int*)w;         w += (size_t)N_NODES * 4;
    float* norm = (float*)w;       w += (size_t)N_NODES * 4;
    float* tvec = (float*)w;       w += (size_t)N_NODES * 4;
    float* qv = (float*)w;         w += (size_t)N_NODES * 4;
    int* rowptr = (int*)w;         w += (size_t)(N_NODES + 64) * 4;
    int* ssrc = (int*)w;           w += (size_t)N_EDGES * 4;
    unsigned short* Xb = (unsigned short*)w;   w += (size_t)N_NODES * DIN * 2;
    unsigned short* W1T = (unsigned short*)w;  w += (size_t)DIN * DH * 2;
    unsigned short* WmuT = (unsigned short*)w; w += (size_t)DH * DZ * 2;
    unsigned short* g1 = (unsigned short*)w;   w += (size_t)N_NODES * DH * 2;
    unsigned short* G2 = (unsigned short*)w;   w += (size_t)N_NODES * DH * 2;
    unsigned short* Pb = (unsigned short*)w;   w += (size_t)N_NODES * DZ * 2;
    unsigned short* Zb = (unsigned short*)w;   w += (size_t)N_NODES * DZ * 2;

    float* out_zzt = (float*)d_out;
    float* out_mus = out_zzt + (size_t)N_NODES * N_NODES;
    float* out_logs = out_mus + (size_t)N_NODES * DZ;

    hipMemsetAsync(d_ws, 0, (size_t)N_NODES * 8, stream);  // deg + cursor
    k_prep<<<8256, 256, 0, stream>>>(X, Xb, W1, W1T, Wmu, WmuT, edst, deg);
    k_scan<<<1, 1024, 0, stream>>>(deg, rowptr, norm);
    k_scatter<<<N_EDGES / 256, 256, 0, stream>>>(esrc, edst, rowptr, cursor, ssrc);
    k_gemm1<<<dim3(N_NODES / 256, 2), 512, 0, stream>>>(Xb, W1T, b1, norm, g1);
    k_agg1<<<N_NODES / 4, 256, 0, stream>>>(g1, rowptr, ssrc, norm, Wsig, G2, tvec, qv);
    k_gemm2<<<N_NODES / 128, 256, 0, stream>>>(G2, WmuT, Pb);
    k_agg2<<<N_NODES / 4, 256, 0, stream>>>(Pb, qv, rowptr, ssrc, norm, tvec, bmu, bsig, eps,
                                            out_mus, out_logs, Zb);
    k_zzt<<<dim3(N_NODES / 64, N_NODES / 256), 256, 0, stream>>>(Zb, out_zzt);
}